// Round 1
// baseline (1090.817 us; speedup 1.0000x reference)
//
#include <hip/hip_runtime.h>

#define N_NODES 100000
#define D_NODE 128
#define N_EDGES 1000000
#define D_EDGE 32
#define H1 128
#define H2 64

// ---------------------------------------------------------------------------
// Kernel A: per-node precompute.
//   P[n][j] = sum_k x[n][k] * W1[k][j]       + b1[j]   (origin part, j<128)
//   Q[n][j] = sum_k x[n][k] * W1[128+k][j]             (dest part)
// Tile: 32 nodes x 256 output cols per block (100000 = 3125 * 32 exactly).
// Thread t: col group c = t&63 (4 cols), node group ng = t>>6 (8 nodes).
// ---------------------------------------------------------------------------
__global__ __launch_bounds__(256) void precompute_kernel(
    const float* __restrict__ x, const float* __restrict__ W1,
    const float* __restrict__ b1, float* __restrict__ P, float* __restrict__ Q)
{
    __shared__ __align__(16) float xs[32][D_NODE];   // 16 KB
    const int nb = blockIdx.x * 32;
    const int t  = threadIdx.x;

    // stage x tile: 4096 floats = 1024 float4, coalesced
    {
        const float4* xg  = (const float4*)(x + (size_t)nb * D_NODE);
        float4*       xsv = (float4*)&xs[0][0];
        #pragma unroll
        for (int i = 0; i < 4; ++i) xsv[t + i * 256] = xg[t + i * 256];
    }
    __syncthreads();

    const int c  = t & 63;   // cols 4c..4c+3 of the 256 merged outputs
    const int ng = t >> 6;   // nodes ng*8 .. ng*8+7

    const bool  isP = (c < 32);
    const float* wp = isP ? (W1 + 4 * c) : (W1 + 128 * 128 + 4 * (c - 32));

    float bias[4];
    #pragma unroll
    for (int i = 0; i < 4; ++i) bias[i] = isP ? b1[4 * c + i] : 0.0f;

    float acc[4][8];
    #pragma unroll
    for (int i = 0; i < 4; ++i)
        #pragma unroll
        for (int n = 0; n < 8; ++n) acc[i][n] = bias[i];

    for (int k4 = 0; k4 < 32; ++k4) {
        float wr[4][4];                 // [k-sub][col]
        #pragma unroll
        for (int kk = 0; kk < 4; ++kk)
            *(float4*)&wr[kk][0] = *(const float4*)(wp + (size_t)(k4 * 4 + kk) * 128);
        #pragma unroll
        for (int n8 = 0; n8 < 8; ++n8) {
            float4 xv = *(const float4*)&xs[ng * 8 + n8][k4 * 4];
            float xa[4] = {xv.x, xv.y, xv.z, xv.w};
            #pragma unroll
            for (int kk = 0; kk < 4; ++kk)
                #pragma unroll
                for (int i = 0; i < 4; ++i)
                    acc[i][n8] += wr[kk][i] * xa[kk];
        }
    }

    float* dst = isP ? (P + 4 * c) : (Q + 4 * (c - 32));
    #pragma unroll
    for (int n8 = 0; n8 < 8; ++n8) {
        int n = nb + ng * 8 + n8;
        float4 v = make_float4(acc[0][n8], acc[1][n8], acc[2][n8], acc[3][n8]);
        *(float4*)(dst + (size_t)n * H1) = v;
    }
}

// ---------------------------------------------------------------------------
// Kernel B: per-edge MLP. 16 edges per round, grid-stride over rounds.
//   h1 = leaky(P[o] + Q[d] + e @ W1c)        (W1c = W1 rows 256..287)
//   h2 = leaky(h1 @ W2 + b2)
//   out = h2 @ W3 + b3
// W1c column (32 regs) and W2 quarter-column (32 regs) persist in VGPRs.
// ---------------------------------------------------------------------------
__global__ __launch_bounds__(256) void edge_kernel(
    const int* __restrict__ ei, const float* __restrict__ ef_g,
    const float* __restrict__ W1, const float* __restrict__ W2,
    const float* __restrict__ b2, const float* __restrict__ W3,
    const float* __restrict__ b3, const float* __restrict__ P,
    const float* __restrict__ Q, float* __restrict__ out)
{
    __shared__ __align__(16) float efs[16][D_EDGE];   // 2 KB
    __shared__ int   oi[16], di[16];
    __shared__ __align__(16) float h1s[16][H1];       // 8 KB
    __shared__ __align__(16) float h2p[16][4][H2];    // 16 KB
    __shared__ float b2s[H2];
    __shared__ float w3s[H2];
    __shared__ float b3s;

    const int t    = threadIdx.x;
    const int j    = t & 127;   // phase-1 column
    const int esub = t >> 7;    // phase-1 edge subset (0/1)
    const int i2   = t & 63;    // phase-2 output channel
    const int p2   = t >> 6;    // phase-2 k-part (0..3), wave-uniform

    // persistent register weights (loaded once per block, coalesced)
    float w1r[32];
    #pragma unroll
    for (int k = 0; k < 32; ++k) w1r[k] = W1[(size_t)(256 + k) * 128 + j];
    float w2r[32];
    #pragma unroll
    for (int r = 0; r < 32; ++r) w2r[r] = W2[(size_t)(p2 * 32 + r) * 64 + i2];

    if (t < H2)                 b2s[t]      = b2[t];
    else if (t < 2 * H2)        w3s[t - 64] = W3[t - 64];
    if (t == 255)               b3s         = b3[0];

    const int nrounds = N_EDGES / 16;   // 62500, exact
    for (int r = blockIdx.x; r < nrounds; r += gridDim.x) {
        const int e0 = r * 16;

        // ---- stage edge features + indices ----
        if (t < 128)
            ((float4*)&efs[0][0])[t] = ((const float4*)(ef_g + (size_t)e0 * D_EDGE))[t];
        else if (t < 144)
            oi[t - 128] = ei[e0 + (t - 128)];
        else if (t < 160)
            di[t - 144] = ei[N_EDGES + e0 + (t - 144)];
        __syncthreads();

        // ---- phase 1: h1 = leaky(eW1c + P[o] + Q[d]) ----
        {
            float pv[8], qv[8];
            #pragma unroll
            for (int e8 = 0; e8 < 8; ++e8) {   // issue gathers early
                int e = esub * 8 + e8;
                pv[e8] = P[(size_t)oi[e] * H1 + j];
                qv[e8] = Q[(size_t)di[e] * H1 + j];
            }
            float acc[8];
            #pragma unroll
            for (int e8 = 0; e8 < 8; ++e8) acc[e8] = 0.0f;
            #pragma unroll
            for (int k4 = 0; k4 < 8; ++k4) {
                #pragma unroll
                for (int e8 = 0; e8 < 8; ++e8) {
                    int e = esub * 8 + e8;
                    float4 ev = *(const float4*)&efs[e][k4 * 4];  // wave-broadcast
                    acc[e8] += ev.x * w1r[k4 * 4 + 0] + ev.y * w1r[k4 * 4 + 1]
                             + ev.z * w1r[k4 * 4 + 2] + ev.w * w1r[k4 * 4 + 3];
                }
            }
            #pragma unroll
            for (int e8 = 0; e8 < 8; ++e8) {
                float v = acc[e8] + pv[e8] + qv[e8];
                v = (v > 0.0f) ? v : 0.01f * v;
                h1s[esub * 8 + e8][j] = v;
            }
        }
        __syncthreads();

        // ---- phase 2: quarter-K partial of h1 @ W2 ----
        {
            #pragma unroll 4
            for (int e = 0; e < 16; ++e) {
                float pa = 0.0f, pb = 0.0f;
                #pragma unroll
                for (int j4 = 0; j4 < 8; j4 += 2) {
                    float4 h0 = *(const float4*)&h1s[e][p2 * 32 + j4 * 4];      // broadcast
                    float4 h1v = *(const float4*)&h1s[e][p2 * 32 + j4 * 4 + 4];
                    pa += h0.x * w2r[j4 * 4 + 0] + h0.y * w2r[j4 * 4 + 1]
                        + h0.z * w2r[j4 * 4 + 2] + h0.w * w2r[j4 * 4 + 3];
                    pb += h1v.x * w2r[j4 * 4 + 4] + h1v.y * w2r[j4 * 4 + 5]
                        + h1v.z * w2r[j4 * 4 + 6] + h1v.w * w2r[j4 * 4 + 7];
                }
                h2p[e][p2][i2] = pa + pb;
            }
        }
        __syncthreads();

        // ---- phase 3: combine parts, leaky, dot with W3, reduce ----
        {
            const int e = t >> 4, l = t & 15;
            float s = 0.0f;
            #pragma unroll
            for (int q = 0; q < 4; ++q) {
                int i = l + q * 16;
                float v = h2p[e][0][i] + h2p[e][1][i] + h2p[e][2][i] + h2p[e][3][i] + b2s[i];
                v = (v > 0.0f) ? v : 0.01f * v;
                s += v * w3s[i];
            }
            s += __shfl_xor(s, 1, 16);
            s += __shfl_xor(s, 2, 16);
            s += __shfl_xor(s, 4, 16);
            s += __shfl_xor(s, 8, 16);
            if (l == 0) out[e0 + e] = s + b3s;
        }
        // no sync needed: next round's LDS writes are fenced by the
        // post-stage / post-phase1 syncs before any conflicting reuse
    }
}

extern "C" void kernel_launch(void* const* d_in, const int* in_sizes, int n_in,
                              void* d_out, int out_size, void* d_ws, size_t ws_size,
                              hipStream_t stream) {
    const float* x   = (const float*)d_in[0];
    const int*   ei  = (const int*)d_in[1];    // edge_index [2][N_EDGES], int32
    const float* ef  = (const float*)d_in[2];
    const float* W1  = (const float*)d_in[3];
    const float* b1  = (const float*)d_in[4];
    const float* W2  = (const float*)d_in[5];
    const float* b2  = (const float*)d_in[6];
    const float* W3  = (const float*)d_in[7];
    const float* b3  = (const float*)d_in[8];
    float*       out = (float*)d_out;

    float* P = (float*)d_ws;                       // [N_NODES][128] fp32
    float* Q = P + (size_t)N_NODES * H1;           // [N_NODES][128] fp32
    // requires ws_size >= 102,400,000 bytes

    precompute_kernel<<<N_NODES / 32, 256, 0, stream>>>(x, W1, b1, P, Q);
    edge_kernel<<<2048, 256, 0, stream>>>(ei, ef, W1, W2, b2, W3, b3, P, Q, out);
}

// Round 2
// 430.964 us; speedup vs baseline: 2.5311x; 2.5311x over previous
//
#include <hip/hip_runtime.h>

#define N_NODES 100000
#define N_EDGES 1000000

typedef __attribute__((ext_vector_type(8))) short bf16x8;
typedef __attribute__((ext_vector_type(4))) float f32x4;

// float -> bf16 (round-to-nearest-even), bit-level, no type gymnastics
static __device__ __forceinline__ short f2bf(float f) {
    unsigned u = __float_as_uint(f);
    u = (u + 0x7fffu + ((u >> 16) & 1u)) >> 16;
    return (short)u;
}

// ---------------------------------------------------------------------------
// Precompute: D[ch=256][node=16] per block-tile via MFMA.
//   merged cols: ch<128 -> P (W1 rows 0..127, +b1), ch>=128 -> Q (W1 rows 128..255)
// Wave w owns chs 64w..64w+63. A = Wm^T (persistent bf16 frags), B = x^T.
// C/D layout: col(node)=lane&15, row(ch)=4*(lane>>4)+reg  [m89-verified]
// ---------------------------------------------------------------------------
__global__ __launch_bounds__(256) void precompute_mfma(
    const float* __restrict__ x, const float* __restrict__ W1,
    const float* __restrict__ b1, float* __restrict__ P, float* __restrict__ Q)
{
    const int t    = threadIdx.x;
    const int lane = t & 63;
    const int w    = t >> 6;
    const int q    = lane >> 4;
    const int n15  = lane & 15;
    const int chb  = 64 * w;

    // A-frags: a[mtl][ks][j] = Wm[k=32ks+8q+j][ch=chb+16mtl+n15]
    bf16x8 afrag[4][4];
    #pragma unroll
    for (int mtl = 0; mtl < 4; ++mtl) {
        const int ch = chb + 16 * mtl + n15;
        const float* wcol = (ch < 128) ? (W1 + ch) : (W1 + 128 * 128 + (ch - 128));
        #pragma unroll
        for (int ks = 0; ks < 4; ++ks)
            #pragma unroll
            for (int j = 0; j < 8; ++j)
                afrag[mtl][ks][j] = f2bf(wcol[(size_t)(32 * ks + 8 * q + j) * 128]);
    }
    float b1r[16];
    #pragma unroll
    for (int mtl = 0; mtl < 4; ++mtl)
        #pragma unroll
        for (int r = 0; r < 4; ++r) {
            const int ch = chb + 16 * mtl + 4 * q + r;
            b1r[mtl * 4 + r] = (ch < 128) ? b1[ch] : 0.0f;
        }

    for (int tile = blockIdx.x; tile < N_NODES / 16; tile += gridDim.x) {
        const int n0 = tile * 16;
        const float* xrow = x + (size_t)(n0 + n15) * 128;

        bf16x8 bfr[4];   // B[k=32ks+8q+j][node=n15]
        #pragma unroll
        for (int ks = 0; ks < 4; ++ks) {
            f32x4 xa = *(const f32x4*)(xrow + 32 * ks + 8 * q);
            f32x4 xb = *(const f32x4*)(xrow + 32 * ks + 8 * q + 4);
            #pragma unroll
            for (int j = 0; j < 4; ++j) { bfr[ks][j] = f2bf(xa[j]); bfr[ks][4 + j] = f2bf(xb[j]); }
        }
        #pragma unroll
        for (int mtl = 0; mtl < 4; ++mtl) {
            f32x4 acc = {0.f, 0.f, 0.f, 0.f};
            #pragma unroll
            for (int ks = 0; ks < 4; ++ks)
                acc = __builtin_amdgcn_mfma_f32_16x16x32_bf16(afrag[mtl][ks], bfr[ks], acc, 0, 0, 0);
            const int ch = chb + 16 * mtl + 4 * q;
            f32x4 outv;
            #pragma unroll
            for (int r = 0; r < 4; ++r) outv[r] = acc[r] + b1r[mtl * 4 + r];
            float* dst = (ch < 128) ? (P + (size_t)(n0 + n15) * 128 + ch)
                                    : (Q + (size_t)(n0 + n15) * 128 + (ch - 128));
            *(f32x4*)dst = outv;
        }
    }
}

// ---------------------------------------------------------------------------
// Edge kernel: each WAVE independently processes 16-edge tiles (no block sync).
//   phase1: D1[ch1=128][e=16] = W1c^T @ ef^T  (8 MFMA) + P/Q fp32 gathers, leaky
//   h1 -> bf16 -> per-wave LDS [edge][ch] (pad 136) -> B-operand frags
//   phase2: D2[ch2=64][e=16] = W2^T @ h1      (16 MFMA)
//   phase3: +b2, leaky, dot W3, reduce over q-lanes, +b3
// ---------------------------------------------------------------------------
__global__ __launch_bounds__(256) void edge_mfma(
    const int* __restrict__ ei, const float* __restrict__ ef,
    const float* __restrict__ W1, const float* __restrict__ W2,
    const float* __restrict__ b2, const float* __restrict__ W3,
    const float* __restrict__ b3, const float* __restrict__ P,
    const float* __restrict__ Q, float* __restrict__ out)
{
    __shared__ unsigned short hbuf[4][16 * 136 + 8];   // per-wave slice, ~17.4 KB
    const int t    = threadIdx.x;
    const int lane = t & 63;
    const int w    = t >> 6;
    const int q    = lane >> 4;
    const int n15  = lane & 15;
    unsigned short* hb = &hbuf[w][0];

    // persistent A-frags: W1c^T  (a1[mt][j] = W1[(256+8q+j)*128 + 16mt+n15])
    bf16x8 a1[8];
    #pragma unroll
    for (int mt = 0; mt < 8; ++mt)
        #pragma unroll
        for (int j = 0; j < 8; ++j)
            a1[mt][j] = f2bf(W1[(size_t)(256 + 8 * q + j) * 128 + 16 * mt + n15]);

    // persistent A-frags: W2^T  (a2[mt2][ks][j] = W2[(32ks+8q+j)*64 + 16mt2+n15])
    bf16x8 a2[4][4];
    #pragma unroll
    for (int mt2 = 0; mt2 < 4; ++mt2)
        #pragma unroll
        for (int ks = 0; ks < 4; ++ks)
            #pragma unroll
            for (int j = 0; j < 8; ++j)
                a2[mt2][ks][j] = f2bf(W2[(size_t)(32 * ks + 8 * q + j) * 64 + 16 * mt2 + n15]);

    float b2r[16], w3r[16];
    #pragma unroll
    for (int mt2 = 0; mt2 < 4; ++mt2)
        #pragma unroll
        for (int r = 0; r < 4; ++r) {
            const int ch = 16 * mt2 + 4 * q + r;
            b2r[mt2 * 4 + r] = b2[ch];
            w3r[mt2 * 4 + r] = W3[ch];
        }
    const float b3v = b3[0];

    const int nTiles  = N_EDGES / 16;          // 62500
    const int wid     = blockIdx.x * 4 + w;
    const int wstride = gridDim.x * 4;

    for (int tile = wid; tile < nTiles; tile += wstride) {
        const int e0 = tile * 16;
        const int oi = ei[e0 + n15];               // edge = column = n15
        const int di = ei[N_EDGES + e0 + n15];

        // ef B-frag: B[k=8q+j][edge=n15]
        const float* efp = ef + (size_t)(e0 + n15) * 32 + 8 * q;
        f32x4 ea = *(const f32x4*)(efp);
        f32x4 eb = *(const f32x4*)(efp + 4);
        bf16x8 bef;
        #pragma unroll
        for (int j = 0; j < 4; ++j) { bef[j] = f2bf(ea[j]); bef[4 + j] = f2bf(eb[j]); }

        // fp32 P/Q gathers along channel axis (dwordx4 each)
        const float* prow = P + (size_t)oi * 128 + 4 * q;
        const float* qrow = Q + (size_t)di * 128 + 4 * q;
        f32x4 pv[8], qv[8];
        #pragma unroll
        for (int mt = 0; mt < 8; ++mt) {
            pv[mt] = *(const f32x4*)(prow + 16 * mt);
            qv[mt] = *(const f32x4*)(qrow + 16 * mt);
        }

        // phase 1: per m-tile MFMA + epilogue, h1 -> LDS as bf16
        #pragma unroll
        for (int mt = 0; mt < 8; ++mt) {
            f32x4 z = {0.f, 0.f, 0.f, 0.f};
            f32x4 h = __builtin_amdgcn_mfma_f32_16x16x32_bf16(a1[mt], bef, z, 0, 0, 0);
            unsigned short hs[4];
            #pragma unroll
            for (int r = 0; r < 4; ++r) {
                float v = h[r] + pv[mt][r] + qv[mt][r];
                v = (v > 0.0f) ? v : 0.01f * v;
                hs[r] = (unsigned short)f2bf(v);
            }
            const int base = n15 * 136 + 16 * mt + 4 * q;   // [edge][ch], ch=16mt+4q+r
            *(unsigned int*)&hb[base]     = (unsigned int)hs[0] | ((unsigned int)hs[1] << 16);
            *(unsigned int*)&hb[base + 2] = (unsigned int)hs[2] | ((unsigned int)hs[3] << 16);
        }
        __asm__ __volatile__("s_waitcnt lgkmcnt(0)" ::: "memory");

        // phase 2: acc2[mt2] += W2^T-frag * h1-frag
        f32x4 acc2[4] = {{0.f,0.f,0.f,0.f},{0.f,0.f,0.f,0.f},{0.f,0.f,0.f,0.f},{0.f,0.f,0.f,0.f}};
        #pragma unroll
        for (int ks = 0; ks < 4; ++ks) {
            bf16x8 hfrag = *(const bf16x8*)&hb[n15 * 136 + 32 * ks + 8 * q];  // 16B-aligned
            #pragma unroll
            for (int mt2 = 0; mt2 < 4; ++mt2)
                acc2[mt2] = __builtin_amdgcn_mfma_f32_16x16x32_bf16(a2[mt2][ks], hfrag, acc2[mt2], 0, 0, 0);
        }

        // phase 3: bias, leaky, dot W3, reduce across q-lane groups
        float s = 0.0f;
        #pragma unroll
        for (int mt2 = 0; mt2 < 4; ++mt2)
            #pragma unroll
            for (int r = 0; r < 4; ++r) {
                float v = acc2[mt2][r] + b2r[mt2 * 4 + r];
                v = (v > 0.0f) ? v : 0.01f * v;
                s += v * w3r[mt2 * 4 + r];
            }
        s += __shfl_xor(s, 16);
        s += __shfl_xor(s, 32);
        if (q == 0) out[e0 + n15] = s + b3v;
    }
}

extern "C" void kernel_launch(void* const* d_in, const int* in_sizes, int n_in,
                              void* d_out, int out_size, void* d_ws, size_t ws_size,
                              hipStream_t stream) {
    const float* x   = (const float*)d_in[0];
    const int*   ei  = (const int*)d_in[1];
    const float* ef  = (const float*)d_in[2];
    const float* W1  = (const float*)d_in[3];
    const float* b1  = (const float*)d_in[4];
    const float* W2  = (const float*)d_in[5];
    const float* b2  = (const float*)d_in[6];
    const float* W3  = (const float*)d_in[7];
    const float* b3  = (const float*)d_in[8];
    float*       out = (float*)d_out;

    float* P = (float*)d_ws;                      // [N_NODES][128] fp32 (+b1 baked)
    float* Q = P + (size_t)N_NODES * 128;         // [N_NODES][128] fp32

    precompute_mfma<<<625, 256, 0, stream>>>(x, W1, b1, P, Q);
    edge_mfma<<<768, 256, 0, stream>>>(ei, ef, W1, W2, b2, W3, b3, P, Q, out);
}

// Round 3
// 343.668 us; speedup vs baseline: 3.1740x; 1.2540x over previous
//
#include <hip/hip_runtime.h>

#define N_NODES 100000
#define N_EDGES 1000000

typedef __attribute__((ext_vector_type(8))) short bf16x8;
typedef __attribute__((ext_vector_type(4))) float f32x4;

static __device__ __forceinline__ short f2bf(float f) {
    unsigned u = __float_as_uint(f);
    u = (u + 0x7fffu + ((u >> 16) & 1u)) >> 16;
    return (short)u;
}
static __device__ __forceinline__ float bf2f(unsigned short s) {
    return __uint_as_float(((unsigned)s) << 16);
}
static __device__ __forceinline__ float lrelu(float x) {
    return fmaxf(x, 0.01f * x);   // 0.01x > x iff x < 0
}

// ---------------------------------------------------------------------------
// Precompute: P/Q as bf16 in gather-swizzled layout.
//   merged ch in [0,256): ch<128 -> P (+b1), else Q.  mt=chP>>4, q=(chP>>2)&3,
//   r=chP&3 ; storage pos within 128-elem row = q*32 + mt*4 + r.
// Wave w owns chs 64w..64w+63; C/D layout col=node=lane&15, row=4*(lane>>4)+reg.
// ---------------------------------------------------------------------------
__global__ __launch_bounds__(256) void precompute_mfma(
    const float* __restrict__ x, const float* __restrict__ W1,
    const float* __restrict__ b1, unsigned short* __restrict__ Pb,
    unsigned short* __restrict__ Qb)
{
    const int t    = threadIdx.x;
    const int lane = t & 63;
    const int w    = t >> 6;
    const int q    = lane >> 4;
    const int n15  = lane & 15;
    const int chb  = 64 * w;

    bf16x8 afrag[4][4];
    #pragma unroll
    for (int mtl = 0; mtl < 4; ++mtl) {
        const int ch = chb + 16 * mtl + n15;
        const float* wcol = (ch < 128) ? (W1 + ch) : (W1 + 128 * 128 + (ch - 128));
        #pragma unroll
        for (int ks = 0; ks < 4; ++ks)
            #pragma unroll
            for (int j = 0; j < 8; ++j)
                afrag[mtl][ks][j] = f2bf(wcol[(size_t)(32 * ks + 8 * q + j) * 128]);
    }
    float b1r[16];
    #pragma unroll
    for (int mtl = 0; mtl < 4; ++mtl)
        #pragma unroll
        for (int r = 0; r < 4; ++r) {
            const int ch = chb + 16 * mtl + 4 * q + r;
            b1r[mtl * 4 + r] = (ch < 128) ? b1[ch] : 0.0f;
        }

    unsigned short* tbase = (w < 2) ? Pb : Qb;
    const int mtb = 4 * (w & 1);   // mt base within table

    for (int tile = blockIdx.x; tile < N_NODES / 16; tile += gridDim.x) {
        const int n0 = tile * 16;
        const float* xrow = x + (size_t)(n0 + n15) * 128;

        bf16x8 bfr[4];
        #pragma unroll
        for (int ks = 0; ks < 4; ++ks) {
            f32x4 xa = *(const f32x4*)(xrow + 32 * ks + 8 * q);
            f32x4 xb = *(const f32x4*)(xrow + 32 * ks + 8 * q + 4);
            #pragma unroll
            for (int j = 0; j < 4; ++j) { bfr[ks][j] = f2bf(xa[j]); bfr[ks][4 + j] = f2bf(xb[j]); }
        }
        #pragma unroll
        for (int mtl = 0; mtl < 4; ++mtl) {
            f32x4 acc = {0.f, 0.f, 0.f, 0.f};
            #pragma unroll
            for (int ks = 0; ks < 4; ++ks)
                acc = __builtin_amdgcn_mfma_f32_16x16x32_bf16(afrag[mtl][ks], bfr[ks], acc, 0, 0, 0);
            unsigned short hs[4];
            #pragma unroll
            for (int r = 0; r < 4; ++r) hs[r] = (unsigned short)f2bf(acc[r] + b1r[mtl * 4 + r]);
            unsigned* dst = (unsigned*)(tbase + (size_t)(n0 + n15) * 128 + q * 32 + (mtb + mtl) * 4);
            dst[0] = (unsigned)hs[0] | ((unsigned)hs[1] << 16);
            dst[1] = (unsigned)hs[2] | ((unsigned)hs[3] << 16);
        }
    }
}

// ---------------------------------------------------------------------------
// Edge kernel, software-pipelined; wave-private 16-edge tiles, no block sync.
// ---------------------------------------------------------------------------
__global__ __launch_bounds__(256, 2) void edge_mfma(
    const int* __restrict__ ei, const float* __restrict__ ef,
    const float* __restrict__ W1, const float* __restrict__ W2,
    const float* __restrict__ b2, const float* __restrict__ W3,
    const float* __restrict__ b3, const unsigned short* __restrict__ Pb,
    const unsigned short* __restrict__ Qb, float* __restrict__ out)
{
    __shared__ unsigned short hbuf[4][16 * 136 + 8];
    const int t    = threadIdx.x;
    const int lane = t & 63;
    const int w    = t >> 6;
    const int q    = lane >> 4;
    const int n15  = lane & 15;
    unsigned short* hb = &hbuf[w][0];

    // persistent A-frags: W1c^T
    bf16x8 a1[8];
    #pragma unroll
    for (int mt = 0; mt < 8; ++mt)
        #pragma unroll
        for (int j = 0; j < 8; ++j)
            a1[mt][j] = f2bf(W1[(size_t)(256 + 8 * q + j) * 128 + 16 * mt + n15]);

    // persistent A-frags: W2^T
    bf16x8 a2[4][4];
    #pragma unroll
    for (int mt2 = 0; mt2 < 4; ++mt2)
        #pragma unroll
        for (int ks = 0; ks < 4; ++ks)
            #pragma unroll
            for (int j = 0; j < 8; ++j)
                a2[mt2][ks][j] = f2bf(W2[(size_t)(32 * ks + 8 * q + j) * 64 + 16 * mt2 + n15]);

    // b2 / W3 packed as bf16 pairs (low = b2, high = W3)
    unsigned b2w3[16];
    #pragma unroll
    for (int mt2 = 0; mt2 < 4; ++mt2)
        #pragma unroll
        for (int r = 0; r < 4; ++r) {
            const int ch = 16 * mt2 + 4 * q + r;
            b2w3[mt2 * 4 + r] = (unsigned)(unsigned short)f2bf(b2[ch])
                              | ((unsigned)(unsigned short)f2bf(W3[ch]) << 16);
        }
    const float b3v = b3[0];

    const int nTiles  = N_EDGES / 16;          // 62500
    const int wid     = blockIdx.x * 4 + w;
    const int wstride = gridDim.x * 4;
    if (wid >= nTiles) return;

    // ---- prologue: prefetch tile 0 ----
    int tile = wid;
    int e0   = tile * 16;
    int oi = ei[e0 + n15];
    int di = ei[N_EDGES + e0 + n15];
    f32x4 ea = *(const f32x4*)(ef + (size_t)(e0 + n15) * 32 + 8 * q);
    f32x4 eb = *(const f32x4*)(ef + (size_t)(e0 + n15) * 32 + 8 * q + 4);
    bf16x8 pvb[4], qvb[4];
    {
        const unsigned short* prow = Pb + (size_t)oi * 128 + q * 32;
        const unsigned short* qrow = Qb + (size_t)di * 128 + q * 32;
        #pragma unroll
        for (int c = 0; c < 4; ++c) {
            pvb[c] = *(const bf16x8*)(prow + 8 * c);
            qvb[c] = *(const bf16x8*)(qrow + 8 * c);
        }
    }

    while (true) {
        const int  next = tile + wstride;
        const bool have = next < nTiles;

        // convert current ef to B-frag
        bf16x8 bef;
        #pragma unroll
        for (int j = 0; j < 4; ++j) { bef[j] = f2bf(ea[j]); bef[4 + j] = f2bf(eb[j]); }

        // prefetch next indices + edge features (issue early)
        int noi = 0, ndi = 0;
        f32x4 nea = ea, neb = eb;
        if (have) {
            const int ne0 = next * 16;
            noi = ei[ne0 + n15];
            ndi = ei[N_EDGES + ne0 + n15];
            nea = *(const f32x4*)(ef + (size_t)(ne0 + n15) * 32 + 8 * q);
            neb = *(const f32x4*)(ef + (size_t)(ne0 + n15) * 32 + 8 * q + 4);
        }

        // ---- phase 1: 8 MFMA + epilogue (consumes pvb/qvb) -> LDS bf16 ----
        #pragma unroll
        for (int mt = 0; mt < 8; ++mt) {
            f32x4 z = {0.f, 0.f, 0.f, 0.f};
            f32x4 h = __builtin_amdgcn_mfma_f32_16x16x32_bf16(a1[mt], bef, z, 0, 0, 0);
            const int c = mt >> 1, off = (mt & 1) * 4;
            unsigned short hs[4];
            #pragma unroll
            for (int r = 0; r < 4; ++r) {
                float v = h[r] + bf2f((unsigned short)pvb[c][off + r])
                               + bf2f((unsigned short)qvb[c][off + r]);
                hs[r] = (unsigned short)f2bf(lrelu(v));
            }
            unsigned* d = (unsigned*)&hb[n15 * 136 + 16 * mt + 4 * q];
            d[0] = (unsigned)hs[0] | ((unsigned)hs[1] << 16);
            d[1] = (unsigned)hs[2] | ((unsigned)hs[3] << 16);
        }

        // pvb/qvb now dead: issue next tile's gathers (hidden behind phase2/3)
        if (have) {
            const unsigned short* prow = Pb + (size_t)noi * 128 + q * 32;
            const unsigned short* qrow = Qb + (size_t)ndi * 128 + q * 32;
            #pragma unroll
            for (int c = 0; c < 4; ++c) {
                pvb[c] = *(const bf16x8*)(prow + 8 * c);
                qvb[c] = *(const bf16x8*)(qrow + 8 * c);
            }
        }

        __asm__ __volatile__("s_waitcnt lgkmcnt(0)" ::: "memory");

        // ---- phase 2: 16 MFMA ----
        f32x4 acc2[4] = {{0.f,0.f,0.f,0.f},{0.f,0.f,0.f,0.f},{0.f,0.f,0.f,0.f},{0.f,0.f,0.f,0.f}};
        #pragma unroll
        for (int ks = 0; ks < 4; ++ks) {
            bf16x8 hfrag = *(const bf16x8*)&hb[n15 * 136 + 32 * ks + 8 * q];
            #pragma unroll
            for (int mt2 = 0; mt2 < 4; ++mt2)
                acc2[mt2] = __builtin_amdgcn_mfma_f32_16x16x32_bf16(a2[mt2][ks], hfrag, acc2[mt2], 0, 0, 0);
        }

        // ---- phase 3: bias, leaky, dot W3, 4-way lane reduce ----
        float s = 0.0f;
        #pragma unroll
        for (int mt2 = 0; mt2 < 4; ++mt2)
            #pragma unroll
            for (int r = 0; r < 4; ++r) {
                const unsigned u = b2w3[mt2 * 4 + r];
                float v = acc2[mt2][r] + bf2f((unsigned short)(u & 0xffffu));
                v = lrelu(v);
                s += v * __uint_as_float(u & 0xffff0000u);
            }
        s += __shfl_xor(s, 16);
        s += __shfl_xor(s, 32);
        if (q == 0) out[e0 + n15] = s + b3v;

        if (!have) break;
        tile = next;
        e0   = next * 16;
        oi = noi; di = ndi; ea = nea; eb = neb;
    }
}

extern "C" void kernel_launch(void* const* d_in, const int* in_sizes, int n_in,
                              void* d_out, int out_size, void* d_ws, size_t ws_size,
                              hipStream_t stream) {
    const float* x   = (const float*)d_in[0];
    const int*   ei  = (const int*)d_in[1];
    const float* ef  = (const float*)d_in[2];
    const float* W1  = (const float*)d_in[3];
    const float* b1  = (const float*)d_in[4];
    const float* W2  = (const float*)d_in[5];
    const float* b2  = (const float*)d_in[6];
    const float* W3  = (const float*)d_in[7];
    const float* b3  = (const float*)d_in[8];
    float*       out = (float*)d_out;

    unsigned short* Pb = (unsigned short*)d_ws;           // [N_NODES][128] bf16 swizzled (+b1)
    unsigned short* Qb = Pb + (size_t)N_NODES * 128;      // [N_NODES][128] bf16 swizzled
    // ws usage: 51.2 MB

    precompute_mfma<<<2048, 256, 0, stream>>>(x, W1, b1, Pb, Qb);
    edge_mfma<<<1536, 256, 0, stream>>>(ei, ef, W1, W2, b2, W3, b3, Pb, Qb, out);
}